// Round 9
// baseline (83.408 us; speedup 1.0000x reference)
//
#include <hip/hip_runtime.h>
#include <math.h>

#define T_N 100000
#define H_N 256
#define TM 32                  // tile rows
#define NT32 (T_N / TM)        // 3125 exact, no tail
#define NB_AT 512              // k_at grid: 2 blocks/CU

typedef __attribute__((ext_vector_type(8))) __bf16 bf16x8;
typedef __attribute__((ext_vector_type(4))) __bf16 bf16x4;
typedef __attribute__((ext_vector_type(4))) float f32x4;

// ws layout (bytes):
//       0 : WmT bf16 [256][256]   (131072)
//  131072 : proj f32 [256]        (1024)
//  132096 : At   f32 [100000]     (400000)
//  532096 : part2 float2[512]     (4096)
//  536192 : s1g  f32[256]         (1024)
//  537216 : s0g  f32[256]         (1024)
//  538240 : lse  f32              (4)

__device__ __forceinline__ float tanh_fast(float x) {
    float e = __expf(2.0f * x);
    return 1.0f - 2.0f / (e + 1.0f);
}

// ---------------------------------------------------------------- prep
__global__ __launch_bounds__(256) void k_prep(const float* __restrict__ Wm,
                                              const float* __restrict__ hc,
                                              const float* __restrict__ W1,
                                              __bf16* __restrict__ WmT,
                                              float* __restrict__ proj,
                                              float* __restrict__ s1g,
                                              float* __restrict__ s0g) {
    const int j = blockIdx.x;
    const int t = threadIdx.x;
    WmT[j * H_N + t] = (__bf16)Wm[t * H_N + j];   // B^T, k-contiguous
    __shared__ float red[H_N];
    red[t] = hc[t] * W1[j * H_N + t];
    __syncthreads();
    for (int off = 128; off > 0; off >>= 1) {
        if (t < off) red[t] += red[t + off];
        __syncthreads();
    }
    if (t == 0) proj[j] = red[0];
    if (j == 0) { s1g[t] = 0.0f; s0g[t] = 0.0f; }
}

// ---------------------------------------------------------------- fused At + LSE + ct partials
// 1024 thr = 16 waves. Wave (wr=w>>3, wc=w&7): rows 16wr..+16, cols 32wc..+32.
// B-fragments pinned in registers via asm (64 VGPR, cannot be rematerialized).
// ct partials software-pipelined one tile behind (reads the retired sA buffer
// + broadcast at_final). 2 raw barriers/tile; gloads stay in flight across both.
__global__ __launch_bounds__(1024, 4) void k_at(const float* __restrict__ Mt,
                                                const __bf16* __restrict__ WmT,
                                                const float* __restrict__ proj,
                                                const float* __restrict__ V,
                                                float* __restrict__ At,
                                                float2* __restrict__ part2,
                                                float* __restrict__ s1g,
                                                float* __restrict__ s0g) {
    const int tid = threadIdx.x;
    const int lane = tid & 63;
    const int w = tid >> 6;     // 0..15
    const int wr = w >> 3;      // 0..1
    const int wc = w & 7;       // 0..7
    const int l15 = lane & 15;
    const int lg = lane >> 4;   // 0..3

    struct SMem {
        __align__(16) char sA[2][TM * 512];  // [32][256] bf16, XOR-swizzled
        float part[16][16];                  // [wave][row-in-16-group]
        float at_final[TM];
    };
    __shared__ SMem sm;

    // ---- B fragments in registers, PINNED (asm is the def point -> no remat)
    f32x4 bregf[8][2];
#pragma unroll
    for (int ks = 0; ks < 8; ++ks)
#pragma unroll
        for (int fc = 0; fc < 2; ++fc) {
            bregf[ks][fc] = *(const f32x4*)(
                WmT + (32 * wc + 16 * fc + l15) * H_N + 32 * ks + 8 * lg);
            asm volatile("" : "+v"(bregf[ks][fc]));
        }
    float pj[2], vj[2];
#pragma unroll
    for (int fc = 0; fc < 2; ++fc) {
        const int n = 32 * wc + 16 * fc + l15;
        pj[fc] = proj[n];
        vj[fc] = V[n];
    }

    // staging: 2048 float4 slots; f = i*1024+tid -> row=f>>6, c4=f&63
    float4 R[2];
    auto gload = [&](int tile) {
        const int tt = (tile < NT32) ? tile : (NT32 - 1);
#pragma unroll
        for (int i = 0; i < 2; ++i) {
            const int f = i * 1024 + tid;
            R[i] = *(const float4*)(Mt + (size_t)(tt * TM + (f >> 6)) * H_N + (f & 63) * 4);
        }
    };
    auto dswrite = [&](int buf) {
#pragma unroll
        for (int i = 0; i < 2; ++i) {
            const int f = i * 1024 + tid;
            const int row = f >> 6, c4 = f & 63;
            bf16x4 b;
            b[0] = (__bf16)R[i].x; b[1] = (__bf16)R[i].y;
            b[2] = (__bf16)R[i].z; b[3] = (__bf16)R[i].w;
            *(bf16x4*)(&sm.sA[buf][(row * 512 + c4 * 8) ^ ((row & 7) << 4)]) = b;
        }
    };

    float s1a[4] = {0.f, 0.f, 0.f, 0.f};
    float s0a[4] = {0.f, 0.f, 0.f, 0.f};
    float lm = -1e30f, ls = 0.0f;
    const int r1 = tid & 15;          // ct row pair (r1, r1+16)
    const int c4 = (tid >> 4) & 63;   // ct cols 4c4..+4
    const int cswz = (r1 & 7) << 4;   // same for r1+16

    int tile = blockIdx.x;
    gload(tile);
    dswrite(0);
    __syncthreads();            // one-time full barrier (sA[0] visible)
    gload(tile + NB_AT);        // in flight across the whole first tile

    int cur = 0;
    for (; tile < NT32; tile += NB_AT) {
        // ---- phase A: MFMA on sA[cur] (B from pinned regs)
        f32x4 acc[2];
#pragma unroll
        for (int fc = 0; fc < 2; ++fc) {
            f32x4 z = {0.f, 0.f, 0.f, 0.f};
            acc[fc] = z;
        }
        const int rbase = (16 * wr + l15) * 512;
        const int rswz = ((16 * wr + l15) & 7) << 4;
#pragma unroll
        for (int ks = 0; ks < 8; ++ks) {
            const bf16x8 af = *(const bf16x8*)(
                &sm.sA[cur][rbase + ((64 * ks + 16 * lg) ^ rswz)]);
            acc[0] = __builtin_amdgcn_mfma_f32_16x16x32_bf16(
                af, __builtin_bit_cast(bf16x8, bregf[ks][0]), acc[0], 0, 0, 0);
            acc[1] = __builtin_amdgcn_mfma_f32_16x16x32_bf16(
                af, __builtin_bit_cast(bf16x8, bregf[ks][1]), acc[1], 0, 0, 0);
        }

        // ---- ct partials for the PREVIOUS tile (sA[cur^1] + at_final broadcast)
        if (tile > blockIdx.x) {
            const float a1 = sm.at_final[r1];
            const float a2 = sm.at_final[r1 + 16];
            const bf16x4 x1 = *(const bf16x4*)(&sm.sA[cur ^ 1][(r1 * 512 + c4 * 8) ^ cswz]);
            const bf16x4 x2 = *(const bf16x4*)(&sm.sA[cur ^ 1][((r1 + 16) * 512 + c4 * 8) ^ cswz]);
#pragma unroll
            for (int q = 0; q < 4; ++q) {
                const float xa = (float)x1[q], xb = (float)x2[q];
                s1a[q] += a1 * xa + a2 * xb;
                s0a[q] += xa + xb;
            }
        }

        // ---- epilogue: col-partial row sums over this wave's 32 cols
#pragma unroll
        for (int i = 0; i < 4; ++i) {
            float p = tanh_fast(acc[0][i] + pj[0]) * vj[0]
                    + tanh_fast(acc[1][i] + pj[1]) * vj[1];
            p += __shfl_xor(p, 1);
            p += __shfl_xor(p, 2);
            p += __shfl_xor(p, 4);
            p += __shfl_xor(p, 8);
            if (l15 == 0) sm.part[w][4 * lg + i] = p;
        }

        asm volatile("s_waitcnt lgkmcnt(0)" ::: "memory");
        __builtin_amdgcn_s_barrier();                       // B1 (no vmcnt drain)
        __builtin_amdgcn_sched_barrier(0);

        // ---- phase B: 32 threads assemble At + LSE; everyone stages next tile
        if (tid < TM) {
            const int g0 = (tid >> 4) * 8;
            float at = 0.f;
#pragma unroll
            for (int q = 0; q < 8; ++q) at += sm.part[g0 + q][tid & 15];
            At[tile * TM + tid] = at;
            sm.at_final[tid] = at;
            if (at > lm) { ls = ls * __expf(lm - at) + 1.0f; lm = at; }
            else ls += __expf(at - lm);
        }
        dswrite(cur ^ 1);          // next tile (R loaded one full tile ago)
        gload(tile + 2 * NB_AT);   // stays in flight across B2

        asm volatile("s_waitcnt lgkmcnt(0)" ::: "memory");
        __builtin_amdgcn_s_barrier();                       // B2
        __builtin_amdgcn_sched_barrier(0);
        cur ^= 1;
    }

    // ---- tail: ct partials for the final tile (data now in sA[cur^1])
    {
        const float a1 = sm.at_final[r1];
        const float a2 = sm.at_final[r1 + 16];
        const bf16x4 x1 = *(const bf16x4*)(&sm.sA[cur ^ 1][(r1 * 512 + c4 * 8) ^ cswz]);
        const bf16x4 x2 = *(const bf16x4*)(&sm.sA[cur ^ 1][((r1 + 16) * 512 + c4 * 8) ^ cswz]);
#pragma unroll
        for (int q = 0; q < 4; ++q) {
            const float xa = (float)x1[q], xb = (float)x2[q];
            s1a[q] += a1 * xa + a2 * xb;
            s0a[q] += xa + xb;
        }
    }

    // ---- block reduce of ct partials (reuse sA), then global atomics
    __syncthreads();
    float* red1 = (float*)&sm.sA[0][0];  // [16][256]
    float* red2 = (float*)&sm.sA[1][0];  // [16][256]
#pragma unroll
    for (int q = 0; q < 4; ++q) {
        red1[r1 * 256 + 4 * c4 + q] = s1a[q];
        red2[r1 * 256 + 4 * c4 + q] = s0a[q];
    }
    __syncthreads();
    if (tid < 256) {
        float a = 0.f;
#pragma unroll
        for (int g = 0; g < 16; ++g) a += red1[g * 256 + tid];
        atomicAdd(&s1g[tid], a);
    } else if (tid < 512) {
        const int c = tid - 256;
        float a = 0.f;
#pragma unroll
        for (int g = 0; g < 16; ++g) a += red2[g * 256 + c];
        atomicAdd(&s0g[c], a);
    }

    // ---- block LSE partial (only wave-0 lanes <32 carry data; rest identity)
    if (w == 0) {
#pragma unroll
        for (int d = 1; d < 64; d <<= 1) {
            const float m2 = __shfl_xor(lm, d), s2 = __shfl_xor(ls, d);
            const float M = fmaxf(lm, m2);
            ls = ls * __expf(lm - M) + s2 * __expf(m2 - M);
            lm = M;
        }
        if (lane == 0) part2[blockIdx.x] = make_float2(lm, ls);
    }
}

// ---------------------------------------------------------------- final: LSE + ct
__global__ __launch_bounds__(512) void k_final(const float2* __restrict__ part2,
                                               const float* __restrict__ s1g,
                                               const float* __restrict__ s0g,
                                               float* __restrict__ lse,
                                               float* __restrict__ out) {
    const int tid = threadIdx.x;
    __shared__ float ms[512], ss[512];
    const float2 p = part2[tid];
    ms[tid] = p.x; ss[tid] = p.y;
    __syncthreads();
    for (int off = 256; off > 0; off >>= 1) {
        if (tid < off) {
            const float m2 = ms[tid + off], s2 = ss[tid + off];
            const float M = fmaxf(ms[tid], m2);
            ss[tid] = ss[tid] * __expf(ms[tid] - M) + s2 * __expf(m2 - M);
            ms[tid] = M;
        }
        __syncthreads();
    }
    __shared__ float Ls;
    if (tid == 0) { Ls = ms[0] + logf(ss[0]); *lse = Ls; }
    __syncthreads();
    if (tid < H_N) out[T_N + tid] = s1g[tid] - Ls * s0g[tid];
}

// ---------------------------------------------------------------- alphat = At - LSE
__global__ __launch_bounds__(256) void k_alpha(const float* __restrict__ At,
                                               const float* __restrict__ lse,
                                               float* __restrict__ out) {
    const float L = *lse;
    const int i4 = blockIdx.x * 256 + threadIdx.x;
    if (i4 < T_N / 4) {
        float4 a = *(const float4*)(At + i4 * 4);
        a.x -= L; a.y -= L; a.z -= L; a.w -= L;
        *(float4*)(out + i4 * 4) = a;
    }
}

// ----------------------------------------------------------------
extern "C" void kernel_launch(void* const* d_in, const int* in_sizes, int n_in,
                              void* d_out, int out_size, void* d_ws, size_t ws_size,
                              hipStream_t stream) {
    const float* inputs = (const float*)d_in[0];  // (T, H)
    const float* hc     = (const float*)d_in[1];  // (1, H)
    const float* Wm     = (const float*)d_in[2];  // (H, H)
    const float* V      = (const float*)d_in[3];  // (H, 1)
    const float* W1     = (const float*)d_in[4];  // (H, H)
    float* out = (float*)d_out;                   // [alphat (T) | ct (H)]

    char* ws = (char*)d_ws;
    __bf16* WmT  = (__bf16*)ws;
    float* proj  = (float*)(ws + 131072);
    float* At    = (float*)(ws + 132096);
    float2* p2   = (float2*)(ws + 532096);
    float* s1g   = (float*)(ws + 536192);
    float* s0g   = (float*)(ws + 537216);
    float* lse   = (float*)(ws + 538240);

    k_prep<<<256, 256, 0, stream>>>(Wm, hc, W1, WmT, proj, s1g, s0g);
    k_at<<<NB_AT, 1024, 0, stream>>>(inputs, WmT, proj, V, At, p2, s1g, s0g);
    k_final<<<1, 512, 0, stream>>>(p2, s1g, s0g, lse, out);
    k_alpha<<<98, 256, 0, stream>>>(At, lse, out);
}